// Round 4
// baseline (372.723 us; speedup 1.0000x reference)
//
#include <hip/hip_runtime.h>
#include <hip/hip_bf16.h>

#define Bv 4
#define Tv 2048
#define Ev 1024
#define Hv 16
#define Sv 64

typedef __attribute__((ext_vector_type(8))) short bf16x8;
typedef __attribute__((ext_vector_type(4))) short bf16x4;
typedef __attribute__((ext_vector_type(4))) float f32x4;
typedef __attribute__((ext_vector_type(16))) float f32x16;

__device__ __forceinline__ ushort f2bf(float f) {
    unsigned u = __float_as_uint(f);
    u = (u + 0x7FFFu + ((u >> 16) & 1u)) >> 16;
    return (ushort)u;
}
// RNE pack via v_cvt_pk_bf16_f32 (header lowers to HW instr on gfx950)
__device__ __forceinline__ unsigned pkrn(float a, float b) {
    __hip_bfloat162 t = __float22bfloat162_rn(make_float2(a, b));
    unsigned r; __builtin_memcpy(&r, &t, 4); return r;
}
// truncation pack, 1 VALU op (v_perm_b32): {lo=a_trunc, hi=b_trunc}
__device__ __forceinline__ unsigned pktr(float a, float b) {
    return __builtin_amdgcn_perm(__float_as_uint(b), __float_as_uint(a), 0x07060302u);
}

// async global->LDS, 16B per lane (global_load_lds_dwordx4)
__device__ __forceinline__ void async16(void* lds, const void* g) {
    __builtin_amdgcn_global_load_lds(
        (const __attribute__((address_space(1))) unsigned int*)g,
        (__attribute__((address_space(3))) unsigned int*)lds, 16, 0, 0);
}

// ---------------------------------------------------------------------------
// Kernel 0: cast weights fp32 -> bf16. Blocks 0..1023: Wp. 1024..1026: Wq/Wk/Wv
// Wq folded with (1/32)*log2(e): attn uses exp2 so v_exp_f32 needs no mul.
// ---------------------------------------------------------------------------
__global__ __launch_bounds__(256) void cast_kernel(
    const float* __restrict__ Wp, const float* __restrict__ Wq,
    const float* __restrict__ Wk, const float* __restrict__ Wv,
    ushort* __restrict__ Wpb, ushort* __restrict__ Wqb,
    ushort* __restrict__ Wkb, ushort* __restrict__ Wvb)
{
    int blk = blockIdx.x;
    if (blk < 1024) {
        int i = (blk * 256 + threadIdx.x) * 4;
        float4 v = *(const float4*)(Wp + i);
        uint2 o = {pkrn(v.x, v.y), pkrn(v.z, v.w)};
        *(uint2*)(Wpb + i) = o;
    } else {
        int p = blk - 1024;
        const float* src = (p == 0) ? Wq : ((p == 1) ? Wk : Wv);
        ushort* dst      = (p == 0) ? Wqb : ((p == 1) ? Wkb : Wvb);
        const float scale = (p == 0) ? 0.03125f * 1.4426950408889634f : 1.0f;
        #pragma unroll
        for (int it = 0; it < 4; ++it) {
            int i = (it * 256 + threadIdx.x) * 4;
            float4 v = *(const float4*)(src + i);
            uint2 o = {pkrn(v.x * scale, v.y * scale), pkrn(v.z * scale, v.w * scale)};
            *(uint2*)(dst + i) = o;
        }
    }
}

// ---------------------------------------------------------------------------
// Kernel 1: QKV projection via MFMA, no LDS. (unchanged)
// ---------------------------------------------------------------------------
__global__ __launch_bounds__(192) void qkv_kernel(
    const float* __restrict__ x,
    const ushort* __restrict__ Wqb, const ushort* __restrict__ Wkb,
    const ushort* __restrict__ Wvb,
    ushort* __restrict__ Q, ushort* __restrict__ K, ushort* __restrict__ Vt)
{
    const int tid  = threadIdx.x;
    const int wave = tid >> 6;        // 0=Q 1=K 2=V
    const int lane = tid & 63;
    const int m    = lane & 15;
    const int quad = lane >> 4;

    const ushort* Wsel = (wave == 0) ? Wqb : ((wave == 1) ? Wkb : Wvb);
    bf16x8 wf[4][2];
    #pragma unroll
    for (int ot = 0; ot < 4; ++ot)
        #pragma unroll
        for (int ks = 0; ks < 2; ++ks)
            wf[ot][ks] = *(const bf16x8*)&Wsel[(ot * 16 + m) * 64 + ks * 32 + quad * 8];

    const int tt = blockIdx.x >> 2;   // 0..511 token tile
    const int hg = blockIdx.x & 3;    // head group
    const int g0 = tt * 16;
    const int gm = g0 + m;
    const int b  = g0 >> 11;
    const int t0 = g0 & 2047;

    #pragma unroll
    for (int hi = 0; hi < 4; ++hi) {
        const int h  = hg * 4 + hi;
        const int bh = b * Hv + h;

        bf16x8 xf[2];
        #pragma unroll
        for (int ks = 0; ks < 2; ++ks) {
            const float* src = x + (size_t)gm * Ev + h * Sv + ks * 32 + quad * 8;
            float4 v0 = *(const float4*)src;
            float4 v1 = *(const float4*)(src + 4);
            unsigned pk[4];
            pk[0] = pkrn(v0.x, v0.y); pk[1] = pkrn(v0.z, v0.w);
            pk[2] = pkrn(v1.x, v1.y); pk[3] = pkrn(v1.z, v1.w);
            xf[ks] = *(bf16x8*)pk;
        }

        f32x4 acc[4];
        #pragma unroll
        for (int ot = 0; ot < 4; ++ot) acc[ot] = (f32x4){0.f, 0.f, 0.f, 0.f};

        if (wave < 2) {
            #pragma unroll
            for (int ks = 0; ks < 2; ++ks)
                #pragma unroll
                for (int ot = 0; ot < 4; ++ot)
                    acc[ot] = __builtin_amdgcn_mfma_f32_16x16x32_bf16(
                        wf[ot][ks], xf[ks], acc[ot], 0, 0, 0);
            ushort* dst = ((wave == 0) ? Q : K)
                        + ((size_t)bh * Tv + t0 + m) * Sv + quad * 4;
            #pragma unroll
            for (int ot = 0; ot < 4; ++ot) {
                uint2 w = {pkrn(acc[ot][0], acc[ot][1]), pkrn(acc[ot][2], acc[ot][3])};
                *(uint2*)(dst + ot * 16) = w;
            }
        } else {
            #pragma unroll
            for (int ks = 0; ks < 2; ++ks)
                #pragma unroll
                for (int st = 0; st < 4; ++st)
                    acc[st] = __builtin_amdgcn_mfma_f32_16x16x32_bf16(
                        xf[ks], wf[st][ks], acc[st], 0, 0, 0);
            ushort* vr = Vt + ((size_t)bh * Sv + m) * Tv + t0 + quad * 4;
            #pragma unroll
            for (int st = 0; st < 4; ++st) {
                uint2 w = {pkrn(acc[st][0], acc[st][1]), pkrn(acc[st][2], acc[st][3])};
                *(uint2*)(vr + (size_t)st * 16 * Tv) = w;
            }
        }
    }
}

// ---------------------------------------------------------------------------
// Kernel 2: flash attention v11 — v10's full-rate 32x32x16 math, LDS-FREE.
// v10 counters: MfmaUtil 37, VALU 46, DS port ~70% of wall (3070cy reads +
// 500 staging writes + 1000 conflict cycles per CU-iter) because all 4
// waves re-read IDENTICAL kf/vf frags from LDS and the staged tiles (8KB K
// + 8KB V per iter) are L1/L2-resident anyway (FETCH 28MB ~= one pass of
// K+V; HBM 7%). Per m169 / Common-mistake #7: staging cache-fit data is
// pure overhead. Now kf/vf load straight from global (a K row = one 128B
// line; per-iter block footprint 16KB -> L1 serves the 4-wave redundancy),
// both __syncthreads() and all bank conflicts are GONE. A bare s_barrier
// per iter keeps waves phase-aligned for L1 temporal locality.
// ---------------------------------------------------------------------------
__global__ __launch_bounds__(256, 4) void attn_kernel(
    const ushort* __restrict__ Q, const ushort* __restrict__ K,
    const ushort* __restrict__ Vt, ushort* __restrict__ O)
{
    __shared__ float ll[4][32];           // per-wave 1/lsum bounce

    const int tid  = threadIdx.x;
    const int wave = tid >> 6;
    const int lane = tid & 63;
    const int r31  = lane & 31;
    const int hi   = lane >> 5;
    const int bh   = blockIdx.x & 63;
    const int q0   = (blockIdx.x >> 6) << 7;   // query tile base (128)

    // Q B-frags (col = q = r31, k = ks*16 + hi*8 + j)
    const ushort* Qb = Q + ((size_t)bh * Tv + q0 + wave * 32 + r31) * Sv + hi * 8;
    bf16x8 qf[4];
    #pragma unroll
    for (int ks = 0; ks < 4; ++ks)
        qf[ks] = *(const bf16x8*)(Qb + ks * 16);

    f32x16 oa[2];
    #pragma unroll
    for (int st = 0; st < 2; ++st)
        #pragma unroll
        for (int r = 0; r < 16; ++r)
            oa[st][r] = 0.f;
    float lsum = 0.f;

    // per-lane global bases:
    //   kf(kt,ks) = K[bh][key = k0+kt*32+r31][d = ks*16 + hi*8 .. +7]
    //   vf(st,kc) = Vt[bh][s = st*32+r31][key = k0 + kc*8 .. +7]
    const ushort* Kl = K  + ((size_t)bh * Tv + r31) * Sv + hi * 8;
    const ushort* Vl = Vt + ((size_t)bh * Sv + r31) * Tv;

    for (int k0 = 0; k0 < Tv; k0 += 64) {
        __builtin_amdgcn_s_barrier();   // phase-align waves (L1 locality)

        #pragma unroll
        for (int kt = 0; kt < 2; ++kt) {
            // S^T = K·Q^T (32x32x16): D col = q = r31,
            // row = key_local = (r&3) + 4*hi + 8*(r>>2)
            const ushort* kp_ = Kl + (size_t)(k0 + kt * 32) * Sv;
            f32x16 sacc;
            #pragma unroll
            for (int r = 0; r < 16; ++r) sacc[r] = 0.f;
            #pragma unroll
            for (int ks = 0; ks < 4; ++ks) {
                bf16x8 kf = *(const bf16x8*)(kp_ + ks * 16);
                sacc = __builtin_amdgcn_mfma_f32_32x32x16_bf16(
                    kf, qf[ks], sacc, 0, 0, 0);
            }

            // per 16-key half (kp): exp2 -> pack -> permlane32_swap into
            // full-rate A-frag (k = hi*8+j), then 2 PV MFMAs (s-tiles)
            #pragma unroll
            for (int kp = 0; kp < 2; ++kp) {
                float p[8];
                #pragma unroll
                for (int j = 0; j < 8; ++j)
                    p[j] = __builtin_amdgcn_exp2f(sacc[kp * 8 + j]);
                lsum += ((p[0] + p[1]) + (p[2] + p[3]))
                      + ((p[4] + p[5]) + (p[6] + p[7]));
                unsigned d0 = pktr(p[0], p[1]);
                unsigned d1 = pktr(p[2], p[3]);
                unsigned d2 = pktr(p[4], p[5]);
                unsigned d3 = pktr(p[6], p[7]);
                // d0' = {d0_lo, d2_lo} = w0 ; d2' = {d0_hi, d2_hi} = w2
                asm volatile("v_permlane32_swap_b32 %0, %1"
                             : "+v"(d0), "+v"(d2));
                asm volatile("v_permlane32_swap_b32 %0, %1"
                             : "+v"(d1), "+v"(d3));
                unsigned pw[4] = {d0, d1, d2, d3};
                bf16x8 pf = *(bf16x8*)pw;

                const int kc = (kt * 2 + kp) * 2 + hi;  // V col chunk
                #pragma unroll
                for (int st = 0; st < 2; ++st) {
                    bf16x8 vf = *(const bf16x8*)
                        (Vl + (size_t)st * 32 * Tv + k0 + kc * 8);
                    oa[st] = __builtin_amdgcn_mfma_f32_32x32x16_bf16(
                        pf, vf, oa[st], 0, 0, 0);
                }
            }
        }
    }

    // row sum: halves hold disjoint key sets for the same q -> one xor-32
    lsum += __shfl_xor(lsum, 32, 64);
    if (lane < 32) ll[wave][lane] = 1.0f / lsum;

    float sc[16];
    #pragma unroll
    for (int r = 0; r < 16; ++r)
        sc[r] = ll[wave][(r & 3) + 4 * hi + 8 * (r >> 2)];

    const int b = bh >> 4, h = bh & 15;
    #pragma unroll
    for (int st = 0; st < 2; ++st)
        #pragma unroll
        for (int r = 0; r < 16; ++r) {
            const int q = (r & 3) + 4 * hi + 8 * (r >> 2);
            O[((size_t)(b * Tv + q0 + wave * 32 + q)) * Ev
              + h * Sv + st * 32 + r31] = f2bf(oa[st][r] * sc[r]);
        }
}

// ---------------------------------------------------------------------------
// Kernel 3: output projection, bf16 MFMA (m97 structure, round-0 form).
// ---------------------------------------------------------------------------
__global__ __launch_bounds__(256) void proj_kernel(
    const ushort* __restrict__ A, const ushort* __restrict__ B,
    const float* __restrict__ bp, float* __restrict__ C)
{
    __shared__ ushort Asm[128 * 32];
    __shared__ ushort Bsm[128 * 32];
    const int tid  = threadIdx.x;
    const int wave = tid >> 6;
    const int lane = tid & 63;
    const int m    = lane & 15;
    const int quad = lane >> 4;
    const int wm   = wave >> 1;
    const int wn   = wave & 1;
    const int m0   = blockIdx.x * 128;
    const int n0   = blockIdx.y * 128;

    f32x4 acc[4][4];
    #pragma unroll
    for (int i = 0; i < 4; ++i)
        #pragma unroll
        for (int j = 0; j < 4; ++j)
            acc[i][j] = (f32x4){0.f, 0.f, 0.f, 0.f};

    for (int k0 = 0; k0 < Ev; k0 += 32) {
        __syncthreads();
        #pragma unroll
        for (int j = 0; j < 2; ++j) {
            int c   = j * 256 + tid;
            int row = c >> 2;
            int col = (c & 3) * 8;
            async16(&Asm[c * 8], &A[(size_t)(m0 + row) * Ev + k0 + col]);
            async16(&Bsm[c * 8], &B[(size_t)(n0 + row) * Ev + k0 + col]);
        }
        __syncthreads();

        bf16x8 af[4], bf[4];
        #pragma unroll
        for (int i = 0; i < 4; ++i)
            af[i] = *(const bf16x8*)&Asm[(wm * 64 + i * 16 + m) * 32 + quad * 8];
        #pragma unroll
        for (int j = 0; j < 4; ++j)
            bf[j] = *(const bf16x8*)&Bsm[(wn * 64 + j * 16 + m) * 32 + quad * 8];
        #pragma unroll
        for (int i = 0; i < 4; ++i)
            #pragma unroll
            for (int j = 0; j < 4; ++j)
                acc[i][j] = __builtin_amdgcn_mfma_f32_16x16x32_bf16(
                    af[i], bf[j], acc[i][j], 0, 0, 0);
    }

    float bbv[4];
    #pragma unroll
    for (int j = 0; j < 4; ++j)
        bbv[j] = bp[n0 + wn * 64 + j * 16 + m];

    #pragma unroll
    for (int i = 0; i < 4; ++i)
        #pragma unroll
        for (int j = 0; j < 4; ++j)
            #pragma unroll
            for (int r = 0; r < 4; ++r)
                C[(size_t)(m0 + wm * 64 + i * 16 + quad * 4 + r) * Ev
                  + n0 + wn * 64 + j * 16 + m] = acc[i][j][r] + bbv[j];
}

// ---------------------------------------------------------------------------
// ws layout (ushort units):
//   Q 8.4M | K 8.4M | Vt 8.4M | O 8.4M | Wpb 1M | Wqb 4096 | Wkb 4096 | Wvb 4096
// ---------------------------------------------------------------------------
extern "C" void kernel_launch(void* const* d_in, const int* in_sizes, int n_in,
                              void* d_out, int out_size, void* d_ws, size_t ws_size,
                              hipStream_t stream) {
    const float* x  = (const float*)d_in[0];
    const float* Wk = (const float*)d_in[1];
    const float* Wq = (const float*)d_in[2];
    const float* Wv = (const float*)d_in[3];
    const float* Wp = (const float*)d_in[4];
    const float* bp = (const float*)d_in[5];
    float* out = (float*)d_out;

    ushort* Q   = (ushort*)d_ws;
    ushort* K   = Q   + 8388608;
    ushort* Vt  = K   + 8388608;
    ushort* O   = Vt  + 8388608;
    ushort* Wpb = O   + 8388608;
    ushort* Wqb = Wpb + 1048576;
    ushort* Wkb = Wqb + 4096;
    ushort* Wvb = Wkb + 4096;

    cast_kernel<<<1027, 256, 0, stream>>>(Wp, Wq, Wk, Wv, Wpb, Wqb, Wkb, Wvb);
    qkv_kernel<<<2048, 192, 0, stream>>>(x, Wqb, Wkb, Wvb, Q, K, Vt);
    attn_kernel<<<1024, 256, 0, stream>>>(Q, K, Vt, O);
    proj_kernel<<<dim3(64, 8), 256, 0, stream>>>(O, Wpb, bp, out);
}

// Round 5
// 218.181 us; speedup vs baseline: 1.7083x; 1.7083x over previous
//
#include <hip/hip_runtime.h>
#include <hip/hip_bf16.h>

#define Bv 4
#define Tv 2048
#define Ev 1024
#define Hv 16
#define Sv 64

typedef __attribute__((ext_vector_type(8))) short bf16x8;
typedef __attribute__((ext_vector_type(4))) short bf16x4;
typedef __attribute__((ext_vector_type(4))) float f32x4;
typedef __attribute__((ext_vector_type(16))) float f32x16;

__device__ __forceinline__ ushort f2bf(float f) {
    unsigned u = __float_as_uint(f);
    u = (u + 0x7FFFu + ((u >> 16) & 1u)) >> 16;
    return (ushort)u;
}
// RNE pack via v_cvt_pk_bf16_f32 (header lowers to HW instr on gfx950)
__device__ __forceinline__ unsigned pkrn(float a, float b) {
    __hip_bfloat162 t = __float22bfloat162_rn(make_float2(a, b));
    unsigned r; __builtin_memcpy(&r, &t, 4); return r;
}
// truncation pack, 1 VALU op (v_perm_b32): {lo=a_trunc, hi=b_trunc}
__device__ __forceinline__ unsigned pktr(float a, float b) {
    return __builtin_amdgcn_perm(__float_as_uint(b), __float_as_uint(a), 0x07060302u);
}

// async global->LDS, 16B per lane (global_load_lds_dwordx4)
__device__ __forceinline__ void async16(void* lds, const void* g) {
    __builtin_amdgcn_global_load_lds(
        (const __attribute__((address_space(1))) unsigned int*)g,
        (__attribute__((address_space(3))) unsigned int*)lds, 16, 0, 0);
}

// ---------------------------------------------------------------------------
// Kernel 0: cast weights fp32 -> bf16. Blocks 0..1023: Wp. 1024..1026: Wq/Wk/Wv
// Wq folded with (1/32)*log2(e): attn uses exp2 so v_exp_f32 needs no mul.
// ---------------------------------------------------------------------------
__global__ __launch_bounds__(256) void cast_kernel(
    const float* __restrict__ Wp, const float* __restrict__ Wq,
    const float* __restrict__ Wk, const float* __restrict__ Wv,
    ushort* __restrict__ Wpb, ushort* __restrict__ Wqb,
    ushort* __restrict__ Wkb, ushort* __restrict__ Wvb)
{
    int blk = blockIdx.x;
    if (blk < 1024) {
        int i = (blk * 256 + threadIdx.x) * 4;
        float4 v = *(const float4*)(Wp + i);
        uint2 o = {pkrn(v.x, v.y), pkrn(v.z, v.w)};
        *(uint2*)(Wpb + i) = o;
    } else {
        int p = blk - 1024;
        const float* src = (p == 0) ? Wq : ((p == 1) ? Wk : Wv);
        ushort* dst      = (p == 0) ? Wqb : ((p == 1) ? Wkb : Wvb);
        const float scale = (p == 0) ? 0.03125f * 1.4426950408889634f : 1.0f;
        #pragma unroll
        for (int it = 0; it < 4; ++it) {
            int i = (it * 256 + threadIdx.x) * 4;
            float4 v = *(const float4*)(src + i);
            uint2 o = {pkrn(v.x * scale, v.y * scale), pkrn(v.z * scale, v.w * scale)};
            *(uint2*)(dst + i) = o;
        }
    }
}

// ---------------------------------------------------------------------------
// Kernel 1: QKV projection via MFMA, no LDS. (unchanged)
// ---------------------------------------------------------------------------
__global__ __launch_bounds__(192) void qkv_kernel(
    const float* __restrict__ x,
    const ushort* __restrict__ Wqb, const ushort* __restrict__ Wkb,
    const ushort* __restrict__ Wvb,
    ushort* __restrict__ Q, ushort* __restrict__ K, ushort* __restrict__ Vt)
{
    const int tid  = threadIdx.x;
    const int wave = tid >> 6;        // 0=Q 1=K 2=V
    const int lane = tid & 63;
    const int m    = lane & 15;
    const int quad = lane >> 4;

    const ushort* Wsel = (wave == 0) ? Wqb : ((wave == 1) ? Wkb : Wvb);
    bf16x8 wf[4][2];
    #pragma unroll
    for (int ot = 0; ot < 4; ++ot)
        #pragma unroll
        for (int ks = 0; ks < 2; ++ks)
            wf[ot][ks] = *(const bf16x8*)&Wsel[(ot * 16 + m) * 64 + ks * 32 + quad * 8];

    const int tt = blockIdx.x >> 2;   // 0..511 token tile
    const int hg = blockIdx.x & 3;    // head group
    const int g0 = tt * 16;
    const int gm = g0 + m;
    const int b  = g0 >> 11;
    const int t0 = g0 & 2047;

    #pragma unroll
    for (int hi = 0; hi < 4; ++hi) {
        const int h  = hg * 4 + hi;
        const int bh = b * Hv + h;

        bf16x8 xf[2];
        #pragma unroll
        for (int ks = 0; ks < 2; ++ks) {
            const float* src = x + (size_t)gm * Ev + h * Sv + ks * 32 + quad * 8;
            float4 v0 = *(const float4*)src;
            float4 v1 = *(const float4*)(src + 4);
            unsigned pk[4];
            pk[0] = pkrn(v0.x, v0.y); pk[1] = pkrn(v0.z, v0.w);
            pk[2] = pkrn(v1.x, v1.y); pk[3] = pkrn(v1.z, v1.w);
            xf[ks] = *(bf16x8*)pk;
        }

        f32x4 acc[4];
        #pragma unroll
        for (int ot = 0; ot < 4; ++ot) acc[ot] = (f32x4){0.f, 0.f, 0.f, 0.f};

        if (wave < 2) {
            #pragma unroll
            for (int ks = 0; ks < 2; ++ks)
                #pragma unroll
                for (int ot = 0; ot < 4; ++ot)
                    acc[ot] = __builtin_amdgcn_mfma_f32_16x16x32_bf16(
                        wf[ot][ks], xf[ks], acc[ot], 0, 0, 0);
            ushort* dst = ((wave == 0) ? Q : K)
                        + ((size_t)bh * Tv + t0 + m) * Sv + quad * 4;
            #pragma unroll
            for (int ot = 0; ot < 4; ++ot) {
                uint2 w = {pkrn(acc[ot][0], acc[ot][1]), pkrn(acc[ot][2], acc[ot][3])};
                *(uint2*)(dst + ot * 16) = w;
            }
        } else {
            #pragma unroll
            for (int ks = 0; ks < 2; ++ks)
                #pragma unroll
                for (int st = 0; st < 4; ++st)
                    acc[st] = __builtin_amdgcn_mfma_f32_16x16x32_bf16(
                        xf[ks], wf[st][ks], acc[st], 0, 0, 0);
            ushort* vr = Vt + ((size_t)bh * Sv + m) * Tv + t0 + quad * 4;
            #pragma unroll
            for (int st = 0; st < 4; ++st) {
                uint2 w = {pkrn(acc[st][0], acc[st][1]), pkrn(acc[st][2], acc[st][3])};
                *(uint2*)(vr + (size_t)st * 16 * Tv) = w;
            }
        }
    }
}

// ---------------------------------------------------------------------------
// Kernel 2: flash attention v12 — v10 structure (LDS staging BACK: r4's
// LDS-free direct-global was 3x WORSE, latency-bound at 11% MfmaUtil; LDS
// is the latency sponge) + 64 QUERIES PER WAVE. v10's top pipe was DS at
// ~61%: every wave read the full K/V tile to serve only 32 queries. Now
// each wave runs two 32-query MFMA groups off the SAME kf/vf register
// loads: DS reads/query halved, staging bytes/query halved (block now
// covers 256 queries), MFMA per barrier interval doubled (better drain
// coverage at the new 2 blocks/CU). MFMA/VALU/exp2 totals unchanged.
// Grid 512 = 2 blocks/CU exactly; VGPR ~170 -> 8 waves/CU.
// ---------------------------------------------------------------------------
__global__ __launch_bounds__(256, 2) void attn_kernel(
    const ushort* __restrict__ Q, const ushort* __restrict__ K,
    const ushort* __restrict__ Vt, ushort* __restrict__ O)
{
    __shared__ ushort kl[64 * 64];        // K tile  [key][d]   (swizzled)
    __shared__ ushort vl[64 * 64];        // Vt tile [s][key]   (swizzled)
    __shared__ float  ll[4][64];          // per-wave 1/lsum bounce

    const int tid  = threadIdx.x;
    const int wave = tid >> 6;
    const int lane = tid & 63;
    const int r31  = lane & 31;
    const int hi   = lane >> 5;
    const int bh   = blockIdx.x & 63;
    const int q0   = (blockIdx.x >> 6) << 8;   // query tile base (256)

    // Q B-frags: group g covers queries q0 + wave*64 + g*32 + r31,
    // k = ks*16 + hi*8 + j
    const ushort* Qb = Q + ((size_t)bh * Tv + q0 + wave * 64 + r31) * Sv + hi * 8;
    bf16x8 qf[2][4];
    #pragma unroll
    for (int g = 0; g < 2; ++g)
        #pragma unroll
        for (int ks = 0; ks < 4; ++ks)
            qf[g][ks] = *(const bf16x8*)(Qb + (size_t)g * 32 * Sv + ks * 16);

    f32x16 oa[2][2];
    #pragma unroll
    for (int g = 0; g < 2; ++g)
        #pragma unroll
        for (int st = 0; st < 2; ++st)
            #pragma unroll
            for (int r = 0; r < 16; ++r)
                oa[g][st][r] = 0.f;
    float lsum[2] = {0.f, 0.f};

    const ushort* Kb = K  + (size_t)bh * Tv * Sv;
    const ushort* Vb = Vt + (size_t)bh * Sv * Tv;

    // staging geometry (swizzled): chunk c -> row=c>>3, phys cg=c&7,
    // source col-group = (c&7) ^ (row&7)
    const int r0 = tid >> 3,         cg0 = (tid & 7) ^ (r0 & 7);
    const int r1 = (256 + tid) >> 3, cg1 = ((256 + tid) & 7) ^ (r1 & 7);
    const size_t koff0 = (size_t)r0 * Sv + cg0 * 8;
    const size_t koff1 = (size_t)r1 * Sv + cg1 * 8;
    const size_t voff0 = (size_t)r0 * Tv + cg0 * 8;
    const size_t voff1 = (size_t)r1 * Tv + cg1 * 8;
    const int swz = r31 & 7;

    // softmax + PV for one 32-query group (everything statically indexed)
    auto softpv = [&](const f32x16& sv, float& ls, f32x16* oag, int kp,
                      const bf16x8* vf) {
        float p[8];
        #pragma unroll
        for (int j = 0; j < 8; ++j)
            p[j] = __builtin_amdgcn_exp2f(sv[kp * 8 + j]);
        ls += ((p[0] + p[1]) + (p[2] + p[3]))
            + ((p[4] + p[5]) + (p[6] + p[7]));
        unsigned d0 = pktr(p[0], p[1]);
        unsigned d1 = pktr(p[2], p[3]);
        unsigned d2 = pktr(p[4], p[5]);
        unsigned d3 = pktr(p[6], p[7]);
        asm volatile("v_permlane32_swap_b32 %0, %1" : "+v"(d0), "+v"(d2));
        asm volatile("v_permlane32_swap_b32 %0, %1" : "+v"(d1), "+v"(d3));
        unsigned pw[4] = {d0, d1, d2, d3};
        bf16x8 pf = *(bf16x8*)pw;
        #pragma unroll
        for (int st = 0; st < 2; ++st)
            oag[st] = __builtin_amdgcn_mfma_f32_32x32x16_bf16(
                pf, vf[st], oag[st], 0, 0, 0);
    };

    for (int k0 = 0; k0 < Tv; k0 += 64) {
        __syncthreads();
        async16(&kl[(size_t)tid * 8],         Kb + (size_t)k0 * Sv + koff0);
        async16(&kl[((size_t)tid + 256) * 8], Kb + (size_t)k0 * Sv + koff1);
        async16(&vl[(size_t)tid * 8],         Vb + k0 + voff0);
        async16(&vl[((size_t)tid + 256) * 8], Vb + k0 + voff1);
        __syncthreads();

        #pragma unroll
        for (int kt = 0; kt < 2; ++kt) {
            // kf loaded ONCE, reused for both query groups
            bf16x8 kf[4];
            #pragma unroll
            for (int ks = 0; ks < 4; ++ks)
                kf[ks] = *(const bf16x8*)
                    &kl[(kt * 32 + r31) * 64 + (((ks * 2 + hi) ^ swz) * 8)];

            // S^T = K·Q^T (32x32x16): D col = q = r31,
            // row = key_local = (r&3) + 4*hi + 8*(r>>2)
            f32x16 s0, s1;
            #pragma unroll
            for (int r = 0; r < 16; ++r) { s0[r] = 0.f; s1[r] = 0.f; }
            #pragma unroll
            for (int ks = 0; ks < 4; ++ks)
                s0 = __builtin_amdgcn_mfma_f32_32x32x16_bf16(
                    kf[ks], qf[0][ks], s0, 0, 0, 0);
            #pragma unroll
            for (int ks = 0; ks < 4; ++ks)
                s1 = __builtin_amdgcn_mfma_f32_32x32x16_bf16(
                    kf[ks], qf[1][ks], s1, 0, 0, 0);

            #pragma unroll
            for (int kp = 0; kp < 2; ++kp) {
                const int kc = (kt * 2 + kp) * 2 + hi;  // V col chunk
                bf16x8 vf[2];
                #pragma unroll
                for (int st = 0; st < 2; ++st)
                    vf[st] = *(const bf16x8*)
                        &vl[(st * 32 + r31) * 64 + ((kc ^ swz) * 8)];
                softpv(s0, lsum[0], oa[0], kp, vf);
                softpv(s1, lsum[1], oa[1], kp, vf);
            }
        }
    }

    // row sum: halves hold disjoint key sets for the same q -> one xor-32
    lsum[0] += __shfl_xor(lsum[0], 32, 64);
    lsum[1] += __shfl_xor(lsum[1], 32, 64);
    if (hi == 0) {
        ll[wave][r31]      = 1.0f / lsum[0];
        ll[wave][32 + r31] = 1.0f / lsum[1];
    }

    const int b = bh >> 4, h = bh & 15;
    #pragma unroll
    for (int g = 0; g < 2; ++g) {
        float sc[16];
        #pragma unroll
        for (int r = 0; r < 16; ++r)
            sc[r] = ll[wave][g * 32 + (r & 3) + 4 * hi + 8 * (r >> 2)];
        #pragma unroll
        for (int st = 0; st < 2; ++st)
            #pragma unroll
            for (int r = 0; r < 16; ++r) {
                const int q = (r & 3) + 4 * hi + 8 * (r >> 2);
                O[((size_t)(b * Tv + q0 + wave * 64 + g * 32 + q)) * Ev
                  + h * Sv + st * 32 + r31] = f2bf(oa[g][st][r] * sc[r]);
            }
    }
}

// ---------------------------------------------------------------------------
// Kernel 3: output projection, bf16 MFMA (m97 structure, round-0 form).
// ---------------------------------------------------------------------------
__global__ __launch_bounds__(256) void proj_kernel(
    const ushort* __restrict__ A, const ushort* __restrict__ B,
    const float* __restrict__ bp, float* __restrict__ C)
{
    __shared__ ushort Asm[128 * 32];
    __shared__ ushort Bsm[128 * 32];
    const int tid  = threadIdx.x;
    const int wave = tid >> 6;
    const int lane = tid & 63;
    const int m    = lane & 15;
    const int quad = lane >> 4;
    const int wm   = wave >> 1;
    const int wn   = wave & 1;
    const int m0   = blockIdx.x * 128;
    const int n0   = blockIdx.y * 128;

    f32x4 acc[4][4];
    #pragma unroll
    for (int i = 0; i < 4; ++i)
        #pragma unroll
        for (int j = 0; j < 4; ++j)
            acc[i][j] = (f32x4){0.f, 0.f, 0.f, 0.f};

    for (int k0 = 0; k0 < Ev; k0 += 32) {
        __syncthreads();
        #pragma unroll
        for (int j = 0; j < 2; ++j) {
            int c   = j * 256 + tid;
            int row = c >> 2;
            int col = (c & 3) * 8;
            async16(&Asm[c * 8], &A[(size_t)(m0 + row) * Ev + k0 + col]);
            async16(&Bsm[c * 8], &B[(size_t)(n0 + row) * Ev + k0 + col]);
        }
        __syncthreads();

        bf16x8 af[4], bf[4];
        #pragma unroll
        for (int i = 0; i < 4; ++i)
            af[i] = *(const bf16x8*)&Asm[(wm * 64 + i * 16 + m) * 32 + quad * 8];
        #pragma unroll
        for (int j = 0; j < 4; ++j)
            bf[j] = *(const bf16x8*)&Bsm[(wn * 64 + j * 16 + m) * 32 + quad * 8];
        #pragma unroll
        for (int i = 0; i < 4; ++i)
            #pragma unroll
            for (int j = 0; j < 4; ++j)
                acc[i][j] = __builtin_amdgcn_mfma_f32_16x16x32_bf16(
                    af[i], bf[j], acc[i][j], 0, 0, 0);
    }

    float bbv[4];
    #pragma unroll
    for (int j = 0; j < 4; ++j)
        bbv[j] = bp[n0 + wn * 64 + j * 16 + m];

    #pragma unroll
    for (int i = 0; i < 4; ++i)
        #pragma unroll
        for (int j = 0; j < 4; ++j)
            #pragma unroll
            for (int r = 0; r < 4; ++r)
                C[(size_t)(m0 + wm * 64 + i * 16 + quad * 4 + r) * Ev
                  + n0 + wn * 64 + j * 16 + m] = acc[i][j][r] + bbv[j];
}

// ---------------------------------------------------------------------------
// ws layout (ushort units):
//   Q 8.4M | K 8.4M | Vt 8.4M | O 8.4M | Wpb 1M | Wqb 4096 | Wkb 4096 | Wvb 4096
// ---------------------------------------------------------------------------
extern "C" void kernel_launch(void* const* d_in, const int* in_sizes, int n_in,
                              void* d_out, int out_size, void* d_ws, size_t ws_size,
                              hipStream_t stream) {
    const float* x  = (const float*)d_in[0];
    const float* Wk = (const float*)d_in[1];
    const float* Wq = (const float*)d_in[2];
    const float* Wv = (const float*)d_in[3];
    const float* Wp = (const float*)d_in[4];
    const float* bp = (const float*)d_in[5];
    float* out = (float*)d_out;

    ushort* Q   = (ushort*)d_ws;
    ushort* K   = Q   + 8388608;
    ushort* Vt  = K   + 8388608;
    ushort* O   = Vt  + 8388608;
    ushort* Wpb = O   + 8388608;
    ushort* Wqb = Wpb + 1048576;
    ushort* Wkb = Wqb + 4096;
    ushort* Wvb = Wkb + 4096;

    cast_kernel<<<1027, 256, 0, stream>>>(Wp, Wq, Wk, Wv, Wpb, Wqb, Wkb, Wvb);
    qkv_kernel<<<2048, 192, 0, stream>>>(x, Wqb, Wkb, Wvb, Q, K, Vt);
    attn_kernel<<<512, 256, 0, stream>>>(Q, K, Vt, O);
    proj_kernel<<<dim3(64, 8), 256, 0, stream>>>(O, Wpb, bp, out);
}